// Round 7
// baseline (88.154 us; speedup 1.0000x reference)
//
#include <hip/hip_runtime.h>

#define NROWS 131072
#define DDIM  64
#define KCTR  512
#define OUT_W 577                 /* 1 + 64 + 512 */
#define RPB   16                  /* rows per tile */
#define NTILES (NROWS / RPB)      /* 8192 */
#define SPAN_F32 (RPB * OUT_W)    /* 9232 floats = 36928 B */
#define SPAN_V4  (SPAN_F32 / 4)   /* 2308 = 9*256 + 4 */
#define GRID 512                  /* 2 blocks/CU x 256 CU, persistent */
#define ROUNDS (NTILES / GRID)    /* 16, exact */
#define K_HALF_LN2 0.34657359027997264f   /* 0.5*ln(2) */

typedef __attribute__((ext_vector_type(8))) short bfrag8;
typedef __attribute__((ext_vector_type(4))) float f32x4;

__device__ __forceinline__ short f2bf(float f) {
    union { float f; unsigned u; } v; v.f = f;
    return (short)((v.u + 0x8000u) >> 16);   // round-to-nearest
}

// __syncthreads minus the vmcnt(0) drain: waits only LDS ops, leaves global
// stores in flight across the barrier.
__device__ __forceinline__ void lds_barrier() {
    asm volatile("s_waitcnt lgkmcnt(0)" ::: "memory");
    __builtin_amdgcn_s_barrier();
    __builtin_amdgcn_sched_barrier(0);
}

__global__ __launch_bounds__(256, 2) void dicrbf_mfma(
    const float* __restrict__ data,
    const float* __restrict__ centers,
    float* __restrict__ out)
{
    __shared__ __align__(16) float s_span[2][SPAN_F32];  // 73856 B double-buffered
    __shared__ short s_dbf[RPB][72];                     // bf16 data tile
    __shared__ float s_xsq[RPB];
    __shared__ float s_cnorm[KCTR];

    const int t    = threadIdx.x;
    const int lane = t & 63;
    const int wid  = t >> 6;
    const int l15  = lane & 15;
    const int lhi  = lane >> 4;
    const int cbase = wid * 128;          // this wave's 128 centers

    // ---- Prologue A: center norms (f32 exact) -> LDS ----
    for (int k = t; k < KCTR; k += 256) {
        const f32x4* c4 = reinterpret_cast<const f32x4*>(centers + (size_t)k * DDIM);
        float s = 0.f;
#pragma unroll
        for (int i = 0; i < DDIM / 4; ++i) {
            f32x4 u = c4[i];
            s += u[0]*u[0] + u[1]*u[1] + u[2]*u[2] + u[3]*u[3];
        }
        s_cnorm[k] = s;
    }

    // ---- Prologue B: A-fragments (centers, bf16) -> registers (loop-invariant)
    bfrag8 afr[8][2];
#pragma unroll
    for (int mf = 0; mf < 8; ++mf) {
        const float* cp = centers + (size_t)(cbase + mf * 16 + l15) * DDIM + lhi * 8;
#pragma unroll
        for (int ks = 0; ks < 2; ++ks) {
            const f32x4 u0 = *reinterpret_cast<const f32x4*>(cp + ks * 32);
            const f32x4 u1 = *reinterpret_cast<const f32x4*>(cp + ks * 32 + 4);
            bfrag8 fr;
            fr[0] = f2bf(u0[0]); fr[1] = f2bf(u0[1]); fr[2] = f2bf(u0[2]); fr[3] = f2bf(u0[3]);
            fr[4] = f2bf(u1[0]); fr[5] = f2bf(u1[1]); fr[6] = f2bf(u1[2]); fr[7] = f2bf(u1[3]);
            afr[mf][ks] = fr;
        }
    }
    __syncthreads();   // one-time full barrier

    f32x4 cnr[8];
#pragma unroll
    for (int mf = 0; mf < 8; ++mf)
        cnr[mf] = *reinterpret_cast<const f32x4*>(&s_cnorm[cbase + mf * 16 + lhi * 4]);

    // ---- Persistent tile loop; stores of round r-1 fused into round r ----
    const int r  = t >> 4;      // row within tile
    const int jj = t & 15;      // 4-float chunk within row

    size_t tile = blockIdx.x;
    f32x4 v = *reinterpret_cast<const f32x4*>(data + (tile * RPB + r) * DDIM + jj * 4);

    int p = 0;
    for (int round = 0; round < ROUNDS; ++round, tile += GRID, p ^= 1) {
        float* span = s_span[p];
        const f32x4* prev4 = reinterpret_cast<const f32x4*>(s_span[p ^ 1]);
        const bool do_store = (round > 0);
        f32x4* oprev = reinterpret_cast<f32x4*>(out)
                     + (tile - GRID) * (size_t)SPAN_V4;   // only used if do_store

        // P1: xsq reduce + passthrough + bf16 tile; prefetch next tile
        float s = v[0]*v[0] + v[1]*v[1] + v[2]*v[2] + v[3]*v[3];
        s += __shfl_xor(s, 1);
        s += __shfl_xor(s, 2);
        s += __shfl_xor(s, 4);
        s += __shfl_xor(s, 8);
        if (jj == 0) { s_xsq[r] = s; span[r * OUT_W] = 1.0f; }

        float* spv = &span[r * OUT_W + 1 + jj * 4];
        spv[0] = v[0]; spv[1] = v[1]; spv[2] = v[2]; spv[3] = v[3];

        short b4[4] = { f2bf(v[0]), f2bf(v[1]), f2bf(v[2]), f2bf(v[3]) };
        *reinterpret_cast<uint2*>(&s_dbf[r][jj * 4]) =
            *reinterpret_cast<const uint2*>(b4);

        if (round + 1 < ROUNDS)
            v = *reinterpret_cast<const f32x4*>(
                data + ((tile + GRID) * RPB + r) * DDIM + jj * 4);

        lds_barrier();   // (B1) dbf/xsq/passthrough visible

        // P2: MFMA + epilogue into span[p], prev-span stores interleaved
        const bfrag8 b0 = *reinterpret_cast<const bfrag8*>(&s_dbf[l15][lhi * 8]);
        const bfrag8 b1 = *reinterpret_cast<const bfrag8*>(&s_dbf[l15][32 + lhi * 8]);
        const float xsq = s_xsq[l15];

        f32x4 ld;
        if (do_store) ld = prev4[t];   // chunk 0, read ahead

#pragma unroll
        for (int mf = 0; mf < 8; ++mf) {
            f32x4 acc = (f32x4)(0.f);
            acc = __builtin_amdgcn_mfma_f32_16x16x32_bf16(afr[mf][0], b0, acc, 0, 0, 0);
            acc = __builtin_amdgcn_mfma_f32_16x16x32_bf16(afr[mf][1], b1, acc, 0, 0, 0);

            if (do_store) {                       // one chunk per mf iteration
                f32x4 cur = ld;
                if (mf < 7) ld = prev4[t + (mf + 1) * 256];   // pipeline next
                oprev[t + mf * 256] = cur;
            }

            float* sp = &span[l15 * OUT_W + 1 + DDIM + cbase + mf * 16 + lhi * 4];
#pragma unroll
            for (int k = 0; k < 4; ++k) {
                float d2 = xsq + cnr[mf][k] - 2.0f * acc[k];
                d2 = fmaxf(d2, 0.0f);
                float w = (K_HALF_LN2 * d2) * __log2f(d2);
                sp[k] = (d2 > 0.0f) ? w : 0.0f;
            }
            // pin VMEM ops into this slot; VALU/MFMA/SALU/DS may still move
            __builtin_amdgcn_sched_barrier(0x38F);
        }
        if (do_store) {
            oprev[t + 8 * 256] = prev4[t + 8 * 256];          // chunk 8
            if (t < 4) oprev[2304 + t] = prev4[2304 + t];     // 4 leftover vec4
        }

        lds_barrier();   // (B2) span[p] complete; prev-span reads retired
    }

    // ---- Tail: store the last round's span (index (ROUNDS-1)&1 = 1) ----
    {
        const f32x4* lp = reinterpret_cast<const f32x4*>(s_span[1]);
        f32x4* o4 = reinterpret_cast<f32x4*>(out)
                  + (size_t)(NTILES - GRID + blockIdx.x) * SPAN_V4;
#pragma unroll
        for (int i = 0; i < 9; ++i)
            o4[t + i * 256] = lp[t + i * 256];
        if (t < 4) o4[2304 + t] = lp[2304 + t];
    }
}

extern "C" void kernel_launch(void* const* d_in, const int* in_sizes, int n_in,
                              void* d_out, int out_size, void* d_ws, size_t ws_size,
                              hipStream_t stream) {
    const float* data    = (const float*)d_in[0];
    const float* centers = (const float*)d_in[1];
    float* out = (float*)d_out;

    hipLaunchKernelGGL(dicrbf_mfma, dim3(GRID), dim3(256), 0, stream,
                       data, centers, out);
}